// Round 3
// baseline (39104.156 us; speedup 1.0000x reference)
//
#include <hip/hip_runtime.h>

typedef __attribute__((ext_vector_type(8))) short short8;
typedef __attribute__((ext_vector_type(4))) float f32x4;

#define T_STEPS 512
#define BATCH 64
#define HID 1024
#define NWG 256  // 64 col-blocks x 4 row-blocks; 1 WG per CU

__device__ __forceinline__ unsigned short f2bf(float f) {
  union { float f; unsigned u; } v; v.f = f;
  return (unsigned short)((v.u + 0x7FFFu + ((v.u >> 16) & 1u)) >> 16);
}

// ---------------- conversion ----------------
__global__ void k_f32_to_bf16(const float* __restrict__ src,
                              unsigned short* __restrict__ dst, int n4) {
  int i = blockIdx.x * blockDim.x + threadIdx.x;
  if (i >= n4) return;
  float4 v = ((const float4*)src)[i];
  unsigned long long p = (unsigned long long)f2bf(v.x)
                       | ((unsigned long long)f2bf(v.y) << 16)
                       | ((unsigned long long)f2bf(v.z) << 32)
                       | ((unsigned long long)f2bf(v.w) << 48);
  ((unsigned long long*)dst)[i] = p;
}

__global__ void k_sentinel(float* out) { out[threadIdx.x] = 12345.0f; }

// ---------------- big GEMM: C(M,N) = A(M,K) * B(N,K)^T + bias(N) ----------------
__global__ __launch_bounds__(256) void k_gemm_bias(
    const unsigned short* __restrict__ A,
    const unsigned short* __restrict__ Bm,
    const float* __restrict__ bias,
    float* __restrict__ C) {
  constexpr int K = 1024, N = 3072;
  constexpr int LS = 40;
  __shared__ unsigned short As[128 * LS];
  __shared__ unsigned short Bs[128 * LS];
  const int tid = threadIdx.x;
  const int lane = tid & 63;
  const int w = tid >> 6;
  const int wm = (w >> 1) * 64, wn = (w & 1) * 64;
  const int m0 = blockIdx.y * 128, n0 = blockIdx.x * 128;
  const int q = lane >> 4, ln = lane & 15;
  const int r = tid >> 2;
  const int c8 = (tid & 3) * 8;

  f32x4 acc[4][4] = {};

  for (int k0 = 0; k0 < K; k0 += 32) {
#pragma unroll
    for (int p = 0; p < 2; ++p) {
      int row = r + p * 64;
      *(short8*)&As[row * LS + c8] = *(const short8*)&A[(long)(m0 + row) * K + k0 + c8];
      *(short8*)&Bs[row * LS + c8] = *(const short8*)&Bm[(long)(n0 + row) * K + k0 + c8];
    }
    __syncthreads();
    short8 af[4], bfr[4];
#pragma unroll
    for (int i = 0; i < 4; ++i) af[i] = *(short8*)&As[(wm + i * 16 + ln) * LS + q * 8];
#pragma unroll
    for (int i = 0; i < 4; ++i) bfr[i] = *(short8*)&Bs[(wn + i * 16 + ln) * LS + q * 8];
#pragma unroll
    for (int im = 0; im < 4; ++im)
#pragma unroll
      for (int in = 0; in < 4; ++in)
        acc[im][in] = __builtin_amdgcn_mfma_f32_16x16x32_bf16(af[im], bfr[in], acc[im][in], 0, 0, 0);
    __syncthreads();
  }
#pragma unroll
  for (int im = 0; im < 4; ++im) {
    int mrow = m0 + wm + im * 16 + q * 4;
#pragma unroll
    for (int in = 0; in < 4; ++in) {
      int ncol = n0 + wn + in * 16 + ln;
      float bv = bias[ncol];
#pragma unroll
      for (int j = 0; j < 4; ++j)
        C[(long)(mrow + j) * N + ncol] = acc[im][in][j] + bv;
    }
  }
}

// ---------------- contention-free grid barrier (256 WGs) ----------------
__device__ __forceinline__ void gbar(unsigned* flags, unsigned gen) {
  __syncthreads();
  if (threadIdx.x == 0)
    __hip_atomic_store(&flags[blockIdx.x], gen, __ATOMIC_RELEASE, __HIP_MEMORY_SCOPE_AGENT);
  if (threadIdx.x < 64) {
#pragma unroll
    for (int f = (int)threadIdx.x; f < NWG; f += 64) {
      int spins = 0;
      while (__hip_atomic_load(&flags[f], __ATOMIC_RELAXED,
                               __HIP_MEMORY_SCOPE_AGENT) < gen) {
        __builtin_amdgcn_s_sleep(1);
        if (++spins > (1 << 14)) break;  // failsafe: wrong answer beats a hang
      }
    }
  }
  __builtin_amdgcn_fence(__ATOMIC_ACQUIRE, "agent");
  __syncthreads();
}

// ---------------- persistent GRU recurrence ----------------
// 256 WGs x 256 thr. WG (rb,cb) owns batch rows [rb*16,+16) x cols [cb*16,+16).
// Waves split K=1024 into 4x256; cross-wave reduce via LDS. Weights LDS-resident.
__global__ __launch_bounds__(256, 1) void k_gru_rec(
    const float* __restrict__ gx,           // (T,B,3,H) fp32
    const unsigned short* __restrict__ Wh,  // (3,H,H) bf16, this layer
    unsigned short* __restrict__ h16,       // (B,H) bf16 state (zeroed)
    unsigned short* __restrict__ hr16,      // (B,H) bf16 h*r
    unsigned short* __restrict__ ys16,      // (T,B,H) bf16 (layer 0)
    float* __restrict__ outh,               // (T,B,H) fp32 (layer 1)
    float* __restrict__ outs,               // (B,H) fp32 final state slice
    unsigned* __restrict__ bar, int layer) {
  __shared__ short8 Wf[3 * 32 * 64];   // 96 KB: [gate][kk][lane] fragment order
  __shared__ float red[8 * 288];       // 4 waves x 2 slots, padded
  const int tid = threadIdx.x;
  const int lane = tid & 63;
  const int wv = tid >> 6;
  const int q = lane >> 4, ln = lane & 15;
  const int cb = blockIdx.x & 63, rb = blockIdx.x >> 6;
  const int c0 = cb * 16, r0 = rb * 16;
  const int erow = tid >> 4, ecol = tid & 15;  // this thread's owned element
  const int grow = r0 + erow, gcol = c0 + ecol;

  // stage weights: Wf[(g*32+kk)*64 + lane] = Wh[g][c0+(lane&15)][kk*32+(lane>>4)*8 ..+8]
  for (int i = tid; i < 3 * 32 * 64; i += 256) {
    int g = i >> 11;
    int rem = i & 2047;
    int kk = rem >> 6;
    int l2 = rem & 63;
    int ln2 = l2 & 15, q2 = l2 >> 4;
    Wf[i] = *(const short8*)&Wh[((long)g * HID + (c0 + ln2)) * HID + kk * 32 + q2 * 8];
  }
  __syncthreads();

  unsigned gen = 0;
  const int kbase = wv * 8;      // this wave's K chunk indices [kbase, kbase+8)
  const int arow = r0 + ln;      // A-fragment row (batch) for this lane
  const int ridx = tid + 8 * (tid >> 6);  // padded reduce index for own element

  float hold = 0.f, zreg = 0.f;
  float gr, gz, gc;
  {  // prefetch t=0 gate biases
    long base = ((long)grow * 3) * HID + gcol;
    gr = gx[base]; gz = gx[base + HID]; gc = gx[base + 2 * HID];
  }

  for (int t = 0; t < T_STEPS; ++t) {
    // ---- phase 1: r,z partials over this wave's K-slice ----
    short8 a[8];
#pragma unroll
    for (int u = 0; u < 8; ++u)
      a[u] = *(const short8*)&h16[(long)arow * HID + (kbase + u) * 32 + q * 8];
    f32x4 accr = {0.f, 0.f, 0.f, 0.f}, accz = {0.f, 0.f, 0.f, 0.f};
#pragma unroll
    for (int u = 0; u < 8; ++u) {
      accr = __builtin_amdgcn_mfma_f32_16x16x32_bf16(a[u], Wf[(0 * 32 + kbase + u) * 64 + lane], accr, 0, 0, 0);
      accz = __builtin_amdgcn_mfma_f32_16x16x32_bf16(a[u], Wf[(1 * 32 + kbase + u) * 64 + lane], accz, 0, 0, 0);
    }
#pragma unroll
    for (int j = 0; j < 4; ++j) {
      int e = (q * 4 + j) * 16 + ln;
      int idx = e + 8 * q;
      red[(wv * 2 + 0) * 288 + idx] = accr[j];
      red[(wv * 2 + 1) * 288 + idx] = accz[j];
    }
    __syncthreads();
    {
      float sr = red[0 * 288 + ridx] + red[2 * 288 + ridx] + red[4 * 288 + ridx] + red[6 * 288 + ridx];
      float sz = red[1 * 288 + ridx] + red[3 * 288 + ridx] + red[5 * 288 + ridx] + red[7 * 288 + ridx];
      float rr = 1.0f / (1.0f + __expf(-(gr + sr)));
      zreg = 1.0f / (1.0f + __expf(-(gz + sz)));
      hr16[(long)grow * HID + gcol] = f2bf(hold * rr);
    }
    gbar(bar, ++gen);

    // ---- phase 2: c partials over this wave's K-slice of h*r ----
    short8 b[8];
#pragma unroll
    for (int u = 0; u < 8; ++u)
      b[u] = *(const short8*)&hr16[(long)arow * HID + (kbase + u) * 32 + q * 8];
    f32x4 accc = {0.f, 0.f, 0.f, 0.f};
#pragma unroll
    for (int u = 0; u < 8; ++u)
      accc = __builtin_amdgcn_mfma_f32_16x16x32_bf16(b[u], Wf[(2 * 32 + kbase + u) * 64 + lane], accc, 0, 0, 0);
#pragma unroll
    for (int j = 0; j < 4; ++j) {
      int e = (q * 4 + j) * 16 + ln;
      int idx = e + 8 * q;
      red[(wv * 2) * 288 + idx] = accc[j];
    }
    __syncthreads();
    {
      float sc = red[0 * 288 + ridx] + red[2 * 288 + ridx] + red[4 * 288 + ridx] + red[6 * 288 + ridx];
      float cc = tanhf(gc + sc);
      float hn = zreg * hold + (1.0f - zreg) * cc;
      hold = hn;
      long pos = (long)grow * HID + gcol;
      h16[pos] = f2bf(hn);
      long opos = ((long)t * BATCH + grow) * HID + gcol;
      if (layer == 0) ys16[opos] = f2bf(hn);
      else            outh[opos] = hn;
      if (t == T_STEPS - 1) outs[pos] = hn;
    }
    // prefetch next step's gate biases before the tail barrier
    if (t + 1 < T_STEPS) {
      long base = (((long)(t + 1) * BATCH + grow) * 3) * HID + gcol;
      gr = gx[base]; gz = gx[base + HID]; gc = gx[base + 2 * HID];
    }
    gbar(bar, ++gen);
  }
}

// ---------------- launch ----------------
extern "C" void kernel_launch(void* const* d_in, const int* in_sizes, int n_in,
                              void* d_out, int out_size, void* d_ws, size_t ws_size,
                              hipStream_t stream) {
  const float* x = (const float*)d_in[0];
  const float* Wx = (const float*)d_in[1];
  const float* bx = (const float*)d_in[2];
  const float* Wh = (const float*)d_in[3];
  float* out = (float*)d_out;

  const size_t SZ_GX = (size_t)T_STEPS * BATCH * 3 * HID * 4;
  const size_t SZ_HID = (size_t)T_STEPS * BATCH * HID * 2;
  const size_t SZ_W16 = (size_t)2 * 3 * HID * HID * 2;
  const size_t NEEDED = SZ_GX + SZ_HID + 2 * SZ_W16 +
                        2 * (size_t)BATCH * HID * 2 + 2048;
  if (ws_size < NEEDED) {
    k_sentinel<<<1, 64, 0, stream>>>(out);
    return;
  }

  char* ws = (char*)d_ws;
  size_t off = 0;
  float* gx32 = (float*)(ws + off); off += SZ_GX;
  unsigned short* hid16 = (unsigned short*)(ws + off); off += SZ_HID;
  unsigned short* Wx16 = (unsigned short*)(ws + off); off += SZ_W16;
  unsigned short* Wh16 = (unsigned short*)(ws + off); off += SZ_W16;
  unsigned short* h16 = (unsigned short*)(ws + off); off += (size_t)BATCH * HID * 2;
  unsigned short* hr16 = (unsigned short*)(ws + off); off += (size_t)BATCH * HID * 2;
  unsigned* bar = (unsigned*)(ws + off); off += 2048;

  {
    int n4 = T_STEPS * BATCH * HID / 4;
    k_f32_to_bf16<<<(n4 + 255) / 256, 256, 0, stream>>>(x, hid16, n4);
  }
  {
    int n4 = 2 * 3 * HID * HID / 4;
    k_f32_to_bf16<<<(n4 + 255) / 256, 256, 0, stream>>>(Wx, Wx16, n4);
    k_f32_to_bf16<<<(n4 + 255) / 256, 256, 0, stream>>>(Wh, Wh16, n4);
  }

  float* outh = out;
  float* outs = out + (size_t)T_STEPS * BATCH * HID;

  for (int l = 0; l < 2; ++l) {
    k_gemm_bias<<<dim3(3072 / 128, 32768 / 128), 256, 0, stream>>>(
        hid16, Wx16 + (size_t)l * 3 * HID * HID, bx + (size_t)l * 3 * HID, gx32);
    hipMemsetAsync(h16, 0, (size_t)BATCH * HID * 2, stream);
    hipMemsetAsync(bar, 0, 2048, stream);
    k_gru_rec<<<NWG, 256, 0, stream>>>(
        gx32, Wh16 + (size_t)l * 3 * HID * HID, h16, hr16,
        hid16, outh, outs + (size_t)l * BATCH * HID, bar, l);
  }
}